// Round 2
// baseline (32891.766 us; speedup 1.0000x reference)
//
#include <hip/hip_runtime.h>
#include <hip/hip_cooperative_groups.h>
#include <math.h>

namespace cg = cooperative_groups;

static constexpr int Bc   = 64;
static constexpr int Tc   = 512;
static constexpr int EMBc = 512;
static constexpr int HIDc = 512;
static constexpr int Kc   = 1024;
static constexpr int CH   = 128;   // k-chunk
static constexpr int NCH  = Kc / CH;
static constexpr int NWGc = 256;
static constexpr int THR  = 256;

// dynamic LDS layout (float indices)
static constexpr int LDS_W    = 0;                      // [16][1024]
static constexpr int LDS_COMB = 16 * Kc;                // [2][CH][64]
static constexpr int LDS_PRE  = LDS_COMB + 2 * CH * Bc; // [4][4][64]
static constexpr int LDS_FLOATS = LDS_PRE + 16 * Bc;    // 33792 (132 KB)

typedef const __attribute__((address_space(1))) void* gas_t;
typedef __attribute__((address_space(3))) void* las_t;

__device__ __forceinline__ void gload4(const float* g, float* l) {
    // async global->LDS, 4B/lane; LDS dest = uniform base + lane*4
    __builtin_amdgcn_global_load_lds((gas_t)g, (las_t)l, 4, 0, 0);
}
template<int N> __device__ __forceinline__ void s_wait_vm() {
    asm volatile("s_waitcnt vmcnt(%0)" :: "n"(N) : "memory");
}
__device__ __forceinline__ void s_wait_lgkm() {
    asm volatile("s_waitcnt lgkmcnt(0)" ::: "memory");
}
__device__ __forceinline__ void wgbar() {
    asm volatile("" ::: "memory");
    __builtin_amdgcn_s_barrier();
    asm volatile("" ::: "memory");
}

__global__ __launch_bounds__(THR, 1)
void lstm_persistent(const int* __restrict__ xp,
                     const float* __restrict__ emb,
                     const float* __restrict__ W0,
                     const float* __restrict__ b0,
                     const float* __restrict__ W1,
                     const float* __restrict__ b1,
                     const float* __restrict__ fcw,
                     const float* __restrict__ fcb,
                     float* __restrict__ out,
                     float* __restrict__ ws)
{
    cg::grid_group grid = cg::this_grid();
    extern __shared__ float lds[];

    float* h0g   = ws;                       // [2][HID][B]
    float* h1g   = ws + 2 * HIDc * Bc;       // [2][HID][B]
    float* zeros = ws + 4 * HIDc * Bc;       // [512] always-zero
    unsigned* ctrp = (unsigned*)(ws + 4 * HIDc * Bc + 512);

    const int tid    = threadIdx.x;
    const int wg     = blockIdx.x;
    const bool is_l0 = (wg < 128);
    const int hw     = (is_l0 ? wg : wg - 128) * 4;
    const float* Wb  = is_l0 ? W0 : W1;
    const float* bb  = is_l0 ? b0 : b1;
    const int b_     = tid & 63;
    const int wv     = __builtin_amdgcn_readfirstlane(tid >> 6);

    // ---- init workspace (poisoned by harness; must re-init every call) ----
    for (int i = wg * THR + tid; i < 4 * HIDc * Bc + 512; i += NWGc * THR)
        ws[i] = 0.0f;
    if (wg == 0 && tid == 0) *ctrp = 0u;

    // ---- preload this WG's 16 weight rows into LDS (once) ----
    for (int r = 0; r < 16; ++r) {
        const float4* s = (const float4*)(Wb + (size_t)((r >> 2) * HIDc + hw + (r & 3)) * Kc);
        ((float4*)(lds + LDS_W + r * Kc))[tid] = s[tid];
    }
    float bias[4];
    #pragma unroll
    for (int j = 0; j < 4; ++j) bias[j] = bb[wv * HIDc + hw + j];

    grid.sync();   // init visible grid-wide (only cg sync in the kernel)

    const float* wr = lds + LDS_W + (wv * 4) * Kc;  // this wave's 4 rows
    float* pre = lds + LDS_PRE;
    float cpriv = 0.0f;

    // ---- prefetch chunk0 for w=0 (l0 emb; all 4 waves, 32 rows each) ----
    if (is_l0) {
        const int t0 = xp[b_ * Tc + 0];
        const float* eb = t0 ? emb + (size_t)t0 * EMBc : zeros;
        const float* s = eb + wv * 32;
        float* d = lds + LDS_COMB + (wv * 32) * Bc;
        #pragma unroll
        for (int r = 0; r < 32; ++r) gload4(s + r, d + r * Bc);
    }

    #pragma unroll 1
    for (int w = 0; w <= Tc; ++w) {
        // ---- top barrier: wait for all arrivals of iteration w-1 ----
        if (w > 0) {
            if (tid == 0) {
                const unsigned tgt = (unsigned)NWGc * (unsigned)w;
                while (__hip_atomic_load(ctrp, __ATOMIC_RELAXED,
                                         __HIP_MEMORY_SCOPE_AGENT) < tgt)
                    __builtin_amdgcn_s_sleep(2);
                __threadfence();   // acquire: invalidate stale L1/L2 lines
            }
            wgbar();
        }

        const bool active = is_l0 ? (w < Tc) : (w >= 1);
        const float* h0prev = h0g + ((w - 1) & 1) * HIDc * Bc; // h0(w-1)
        const float* h1prev = h1g + (w & 1) * HIDc * Bc;       // h1(w-2)

        const float* ebase = nullptr;
        if (is_l0 && w < Tc) {
            const int tok = xp[b_ * Tc + w];
            ebase = tok ? emb + (size_t)tok * EMBc : zeros;
        }

        // l1 stages its chunk0 (h0(w-1) rows 0..127) after the barrier
        if (active && !is_l0) {
            const float* s = h0prev + (wv * 32) * Bc + b_;
            float* d = lds + LDS_COMB + (wv * 32) * Bc;
            #pragma unroll
            for (int r = 0; r < 32; ++r) gload4(s + r * Bc, d + r * Bc);
        }

        if (active) {
            float a0 = 0.f, a1 = 0.f, a2 = 0.f, a3 = 0.f;

            #pragma unroll 1
            for (int c = 0; c < NCH; ++c) {
                const float* cb = lds + LDS_COMB + (c & 1) * CH * Bc;
                // A: issue stage(c+1) into the other buffer
                if (c + 1 < NCH) {
                    const int cn = c + 1;
                    float* nb = lds + LDS_COMB + (cn & 1) * CH * Bc;
                    if (is_l0 && cn < 4) {
                        const float* s = ebase + cn * CH + wv * 32;
                        float* d = nb + (wv * 32) * Bc;
                        #pragma unroll
                        for (int r = 0; r < 32; ++r) gload4(s + r, d + r * Bc);
                    } else {
                        const float* hs = is_l0 ? (h0prev + (cn - 4) * CH * Bc)
                                  : (cn < 4 ? (h0prev + cn * CH * Bc)
                                            : (h1prev + (cn - 4) * CH * Bc));
                        const float* s = hs + (wv * 32) * Bc + b_;
                        float* d = nb + (wv * 32) * Bc;
                        #pragma unroll
                        for (int r = 0; r < 32; ++r) gload4(s + r * Bc, d + r * Bc);
                    }
                    s_wait_vm<32>();   // B: chunk c landed (c+1 in flight)
                } else {
                    s_wait_vm<0>();
                }
                wgbar();               // C: chunk c visible to all waves

                // D: GEMV over this chunk — pure LDS
                const float* wc = wr + c * CH;
                #pragma unroll 4
                for (int k4 = 0; k4 < CH / 4; ++k4) {
                    const float x0 = cb[(k4 * 4 + 0) * Bc + b_];
                    const float x1 = cb[(k4 * 4 + 1) * Bc + b_];
                    const float x2 = cb[(k4 * 4 + 2) * Bc + b_];
                    const float x3 = cb[(k4 * 4 + 3) * Bc + b_];
                    const float4 q0 = *(const float4*)(wc + 0 * Kc + k4 * 4);
                    const float4 q1 = *(const float4*)(wc + 1 * Kc + k4 * 4);
                    const float4 q2 = *(const float4*)(wc + 2 * Kc + k4 * 4);
                    const float4 q3 = *(const float4*)(wc + 3 * Kc + k4 * 4);
                    a0 = fmaf(q0.w, x3, fmaf(q0.z, x2, fmaf(q0.y, x1, fmaf(q0.x, x0, a0))));
                    a1 = fmaf(q1.w, x3, fmaf(q1.z, x2, fmaf(q1.y, x1, fmaf(q1.x, x0, a1))));
                    a2 = fmaf(q2.w, x3, fmaf(q2.z, x2, fmaf(q2.y, x1, fmaf(q2.x, x0, a2))));
                    a3 = fmaf(q3.w, x3, fmaf(q3.z, x2, fmaf(q3.y, x1, fmaf(q3.x, x0, a3))));
                }
                if (c + 1 < NCH) wgbar();  // E: release buffer for next stage
            }

            // ---- gate exchange + cell update ----
            pre[(wv * 4 + 0) * Bc + b_] = a0 + bias[0];
            pre[(wv * 4 + 1) * Bc + b_] = a1 + bias[1];
            pre[(wv * 4 + 2) * Bc + b_] = a2 + bias[2];
            pre[(wv * 4 + 3) * Bc + b_] = a3 + bias[3];
            s_wait_lgkm();
            wgbar();
            const float p0 = pre[(0 * 4 + wv) * Bc + b_];
            const float p1 = pre[(1 * 4 + wv) * Bc + b_];
            const float p2 = pre[(2 * 4 + wv) * Bc + b_];
            const float p3 = pre[(3 * 4 + wv) * Bc + b_];
            const float ig = 1.f / (1.f + expf(-p0));
            const float fg = 1.f / (1.f + expf(-p1));
            const float og = 1.f / (1.f + expf(-p2));
            const float gg = fmaxf(p3, 0.f);
            cpriv = fg * cpriv + ig * gg;
            float* hdst = is_l0 ? (h0g + (w & 1) * HIDc * Bc)
                                : (h1g + ((w - 1) & 1) * HIDc * Bc);
            hdst[(hw + wv) * Bc + b_] = og * fmaxf(cpriv, 0.f);  // oldest vmem op
        }

        asm volatile("" ::: "memory");  // keep h-store older than prefetch

        // ---- prefetch next step's chunk0 (l0 emb) on waves 1..3 only ----
        const bool pf = is_l0 && (w + 1 < Tc);
        if (pf && wv > 0) {
            const int tn = xp[b_ * Tc + (w + 1)];
            const float* eb2 = tn ? emb + (size_t)tn * EMBc : zeros;
            const int start = (wv == 1) ? 0 : (wv == 2) ? 43 : 86;
            const int cnt   = (wv == 3) ? 42 : 43;
            const float* s = eb2 + start;
            float* d = lds + LDS_COMB + start * Bc;
            for (int r = 0; r < cnt; ++r) gload4(s + r, d + r * Bc);
        }
        // per-wave drain of the h-store (oldest); prefetch stays in flight
        if (pf) {
            if (wv == 3)      s_wait_vm<42>();
            else if (wv > 0)  s_wait_vm<43>();
            else              s_wait_vm<0>();
        } else {
            s_wait_vm<0>();
        }
        wgbar();   // all threads' h-stores drained to L2
        if (tid == 0) {
            __threadfence();        // release: write back L2 (cross-XCD)
            atomicAdd(ctrp, 1u);    // arrive
        }
    }

    // ---- final FC + sigmoid on h1(T-1) ----
    if (wg == 0) {
        if (tid == 0) {
            const unsigned tgt = (unsigned)NWGc * (unsigned)(Tc + 1);
            while (__hip_atomic_load(ctrp, __ATOMIC_RELAXED,
                                     __HIP_MEMORY_SCOPE_AGENT) < tgt)
                __builtin_amdgcn_s_sleep(2);
            __threadfence();
        }
        wgbar();
        if (tid < Bc) {
            const float* h1f = h1g + ((Tc - 1) & 1) * HIDc * Bc;
            float s = fcb[0];
            for (int h = 0; h < HIDc; ++h)
                s = fmaf(h1f[h * Bc + tid], fcw[h], s);
            out[tid] = 1.f / (1.f + expf(-s));
        }
    }
}

extern "C" void kernel_launch(void* const* d_in, const int* in_sizes, int n_in,
                              void* d_out, int out_size, void* d_ws, size_t ws_size,
                              hipStream_t stream) {
    const int*   xp  = (const int*)d_in[0];
    const float* emb = (const float*)d_in[1];
    const float* W0  = (const float*)d_in[2];
    const float* b0  = (const float*)d_in[3];
    const float* W1  = (const float*)d_in[4];
    const float* b1  = (const float*)d_in[5];
    const float* fcw = (const float*)d_in[6];
    const float* fcb = (const float*)d_in[7];
    float* out = (float*)d_out;
    float* ws  = (float*)d_ws;

    static constexpr int ldsBytes = LDS_FLOATS * 4;
    hipFuncSetAttribute((const void*)lstm_persistent,
                        hipFuncAttributeMaxDynamicSharedMemorySize, ldsBytes);

    void* args[] = { (void*)&xp, (void*)&emb, (void*)&W0, (void*)&b0,
                     (void*)&W1, (void*)&b1, (void*)&fcw, (void*)&fcb,
                     (void*)&out, (void*)&ws };
    hipLaunchCooperativeKernel((void*)lstm_persistent, dim3(NWGc), dim3(THR),
                               args, ldsBytes, stream);
}

// Round 3
// 18668.907 us; speedup vs baseline: 1.7618x; 1.7618x over previous
//
#include <hip/hip_runtime.h>
#include <hip/hip_cooperative_groups.h>
#include <math.h>

namespace cg = cooperative_groups;

static constexpr int Bc   = 64;
static constexpr int Tc   = 512;
static constexpr int EMBc = 512;
static constexpr int HIDc = 512;
static constexpr int Kc   = 1024;
static constexpr int CH   = 128;
static constexpr int THR  = 256;
static constexpr int NWGc = 256;
static constexpr int SLAB = HIDc * Bc;   // 32768 floats = 128 KB

// ws layout (float indices)
static constexpr size_t WS_H0  = 0;                    // [3][SLAB] h0(t) at t%3
static constexpr size_t WS_H1  = WS_H0 + 3ull * SLAB;  // [2][SLAB] h1(t) at t&1
static constexpr size_t WS_XE  = WS_H1 + 2ull * SLAB;  // [3][SLAB] emb slab(t) at t%3
static constexpr size_t WS_CTR = WS_XE + 3ull * SLAB;  // 8 counters, 64B apart
static constexpr size_t WS_END = WS_CTR + 128;

// LDS layout (float indices)
static constexpr int LDS_W    = 0;                      // [16][1024] weights
static constexpr int LDS_COMB = 16 * Kc;                // [2][CH][Bc] staging dbuf
static constexpr int LDS_PRE  = LDS_COMB + 2 * CH * Bc; // [16][Bc] gate exchange
static constexpr int LDS_FLOATS = LDS_PRE + 16 * Bc;    // 33792 floats = 132 KB

typedef const __attribute__((address_space(1))) void* gas_t;
typedef __attribute__((address_space(3))) void* las_t;

__device__ __forceinline__ void st_dev(float* p, float v) {
    __hip_atomic_store(p, v, __ATOMIC_RELAXED, __HIP_MEMORY_SCOPE_AGENT);
}
__device__ __forceinline__ float ld_dev(const float* p) {
    return __hip_atomic_load(p, __ATOMIC_RELAXED, __HIP_MEMORY_SCOPE_AGENT);
}
template<int N> __device__ __forceinline__ void s_wait_vm() {
    asm volatile("s_waitcnt vmcnt(%0)" :: "n"(N) : "memory");
}
__device__ __forceinline__ void s_wait_lgkm() {
    asm volatile("s_waitcnt lgkmcnt(0)" ::: "memory");
}
__device__ __forceinline__ void wgbar() {
    asm volatile("" ::: "memory");
    __builtin_amdgcn_s_barrier();
    asm volatile("" ::: "memory");
}

__global__ __launch_bounds__(THR, 1)
void lstm_persistent(const int* __restrict__ xp,
                     const float* __restrict__ emb,
                     const float* __restrict__ W0,
                     const float* __restrict__ b0,
                     const float* __restrict__ W1,
                     const float* __restrict__ b1,
                     const float* __restrict__ fcw,
                     const float* __restrict__ fcb,
                     float* __restrict__ out,
                     float* __restrict__ ws)
{
    cg::grid_group grid = cg::this_grid();
    extern __shared__ float lds[];

    float*    h0g = ws + WS_H0;
    float*    h1g = ws + WS_H1;
    float*    xeg = ws + WS_XE;
    unsigned* ctr = (unsigned*)(ws + WS_CTR);

    const int  tid   = threadIdx.x;
    const int  wg    = blockIdx.x;
    const bool is_l0 = (wg < 128);
    const int  hw    = (is_l0 ? wg : wg - 128) * 4;
    const float* Wb  = is_l0 ? W0 : W1;
    const float* bb  = is_l0 ? b0 : b1;
    const int  b_    = tid & 63;
    const int  wv    = __builtin_amdgcn_readfirstlane(tid >> 6);

    // ---- init: zero h buffers (coherent stores), counters, slabs 0 & 1 ----
    for (size_t i = (size_t)wg * THR + tid; i < 5ull * SLAB; i += (size_t)NWGc * THR)
        st_dev(ws + i, 0.0f);
    if (wg == 0 && tid < 8)
        __hip_atomic_store(&ctr[tid * 16], 0u, __ATOMIC_RELAXED, __HIP_MEMORY_SCOPE_AGENT);

    const int rrow = tid >> 6;   // 0..3: this thread's k-row within WG's 4 rows
    if (is_l0) {
        #pragma unroll
        for (int wn = 0; wn < 2; ++wn) {
            const int kk  = hw + rrow;
            const int tok = xp[b_ * Tc + wn];
            float v = 0.0f;
            if (tok) v = emb[(size_t)tok * EMBc + kk];
            st_dev(xeg + (size_t)(wn % 3) * SLAB + kk * Bc + b_, v);
        }
    }

    // ---- preload this WG's 16 weight rows into LDS ----
    for (int r = 0; r < 16; ++r) {
        const float4* s = (const float4*)(Wb + (size_t)((r >> 2) * HIDc + hw + (r & 3)) * Kc);
        ((float4*)(lds + LDS_W + r * Kc))[tid] = s[tid];
    }
    float bias[4];
    #pragma unroll
    for (int j = 0; j < 4; ++j) bias[j] = bb[wv * HIDc + hw + j];

    grid.sync();   // only cg sync: init visible grid-wide

    const float* wr  = lds + LDS_W + (wv * 4) * Kc;
    float*       pre = lds + LDS_PRE;
    float cpriv = 0.0f;
    float acc[4];

    // stage 32 rows of chunk c from a [512][64] slab into comb[buf]
    auto stage = [&](int buf, const float* slabBase, int c) {
        const float* s = slabBase + (size_t)(c * CH + wv * 32) * Bc + b_;
        float*       d = lds + LDS_COMB + buf * CH * Bc + (wv * 32) * Bc;
        #pragma unroll
        for (int r = 0; r < 32; ++r)
            __builtin_amdgcn_global_load_lds((gas_t)(s + r * Bc),
                                             (las_t)(d + r * Bc), 4, 0, 16);
    };
    // GEMV over chunk in comb[buf], weight columns at global chunk cglob
    auto gemv = [&](int buf, int cglob) {
        const float* cb = lds + LDS_COMB + buf * CH * Bc;
        const float* wc = wr + cglob * CH;
        #pragma unroll 4
        for (int k4 = 0; k4 < CH / 4; ++k4) {
            const float x0 = cb[(k4 * 4 + 0) * Bc + b_];
            const float x1 = cb[(k4 * 4 + 1) * Bc + b_];
            const float x2 = cb[(k4 * 4 + 2) * Bc + b_];
            const float x3 = cb[(k4 * 4 + 3) * Bc + b_];
            const float4 q0 = *(const float4*)(wc + 0 * Kc + k4 * 4);
            const float4 q1 = *(const float4*)(wc + 1 * Kc + k4 * 4);
            const float4 q2 = *(const float4*)(wc + 2 * Kc + k4 * 4);
            const float4 q3 = *(const float4*)(wc + 3 * Kc + k4 * 4);
            acc[0] = fmaf(q0.w, x3, fmaf(q0.z, x2, fmaf(q0.y, x1, fmaf(q0.x, x0, acc[0]))));
            acc[1] = fmaf(q1.w, x3, fmaf(q1.z, x2, fmaf(q1.y, x1, fmaf(q1.x, x0, acc[1]))));
            acc[2] = fmaf(q2.w, x3, fmaf(q2.z, x2, fmaf(q2.y, x1, fmaf(q2.x, x0, acc[2]))));
            acc[3] = fmaf(q3.w, x3, fmaf(q3.z, x2, fmaf(q3.y, x1, fmaf(q3.x, x0, acc[3]))));
        }
    };
    // 4-chunk double-buffered half (chunks cbase..cbase+3 of the same slab)
    auto half = [&](const float* slabBase, int cbase) {
        stage(0, slabBase, cbase + 0);
        stage(1, slabBase, cbase + 1);
        s_wait_vm<32>(); wgbar();
        gemv(0, cbase + 0); s_wait_lgkm(); wgbar();
        stage(0, slabBase, cbase + 2);
        s_wait_vm<32>(); wgbar();
        gemv(1, cbase + 1); s_wait_lgkm(); wgbar();
        stage(1, slabBase, cbase + 3);
        s_wait_vm<32>(); wgbar();
        gemv(0, cbase + 2); s_wait_lgkm(); wgbar();
        s_wait_vm<0>();  wgbar();
        gemv(1, cbase + 3);
    };

    #pragma unroll 1
    for (int w = 0; w <= Tc + 1; ++w) {
        const bool a0  = is_l0 && (w < Tc);          // layer0 computes t=w
        const bool a1  = !is_l0 && (w >= 2);         // layer1 computes t=w-2
        const bool act = a0 || a1;

        acc[0] = acc[1] = acc[2] = acc[3] = 0.0f;

        // ---- PRE-HALF: barrier-independent input half (chunks 0..3) ----
        if (act) {
            const float* preBase = is_l0 ? (xeg + (size_t)(w % 3) * SLAB)
                                         : (h0g + (size_t)((w - 2) % 3) * SLAB);
            half(preBase, 0);
        }

        // ---- spin barrier w (relaxed; no cache maintenance) ----
        if (tid == 0) {
            const unsigned tgt = (unsigned)NWGc * (unsigned)w;
            for (;;) {
                unsigned s = 0;
                #pragma unroll
                for (int g = 0; g < 8; ++g)
                    s += __hip_atomic_load(&ctr[g * 16], __ATOMIC_RELAXED,
                                           __HIP_MEMORY_SCOPE_AGENT);
                if (s >= tgt) break;
                __builtin_amdgcn_s_sleep(1);
            }
        }
        wgbar();

        // ---- POST-HALF: recurrent input half (chunks 4..7) + cell update ----
        if (act) {
            const float* postBase = is_l0 ? (h0g + (size_t)(((w - 1) + 3) % 3) * SLAB)
                                          : (h1g + (size_t)((w - 3) & 1) * SLAB);
            half(postBase, 4);

            pre[(wv * 4 + 0) * Bc + b_] = acc[0] + bias[0];
            pre[(wv * 4 + 1) * Bc + b_] = acc[1] + bias[1];
            pre[(wv * 4 + 2) * Bc + b_] = acc[2] + bias[2];
            pre[(wv * 4 + 3) * Bc + b_] = acc[3] + bias[3];
            s_wait_lgkm(); wgbar();
            const float p0 = pre[(0 * 4 + wv) * Bc + b_];
            const float p1 = pre[(1 * 4 + wv) * Bc + b_];
            const float p2 = pre[(2 * 4 + wv) * Bc + b_];
            const float p3 = pre[(3 * 4 + wv) * Bc + b_];
            const float ig = 1.f / (1.f + expf(-p0));
            const float fg = 1.f / (1.f + expf(-p1));
            const float og = 1.f / (1.f + expf(-p2));
            const float gg = fmaxf(p3, 0.f);
            cpriv = fg * cpriv + ig * gg;
            const float hn = og * fmaxf(cpriv, 0.f);
            float* hdst = is_l0 ? (h0g + (size_t)(w % 3) * SLAB)
                                : (h1g + (size_t)((w - 2) & 1) * SLAB);
            st_dev(hdst + (hw + wv) * Bc + b_, hn);
        }

        // ---- shared emb transpose for step w+2 (l0 WGs, 4 k-rows each) ----
        if (is_l0 && (w + 2) < Tc) {
            const int wn  = w + 2;
            const int kk  = hw + rrow;
            const int tok = xp[b_ * Tc + wn];
            float v = 0.0f;
            if (tok) v = emb[(size_t)tok * EMBc + kk];
            st_dev(xeg + (size_t)(wn % 3) * SLAB + kk * Bc + b_, v);
        }

        // ---- arrive for barrier w+1 ----
        s_wait_vm<0>();   // all write-through stores acked at coherent point
        wgbar();
        if (tid == 0)
            __hip_atomic_fetch_add(&ctr[(wg & 7) * 16], 1u, __ATOMIC_RELAXED,
                                   __HIP_MEMORY_SCOPE_AGENT);
    }

    // ---- final FC + sigmoid on h1(T-1) (slot (T-1)&1 = 1) ----
    if (wg == 0) {
        if (tid == 0) {
            const unsigned tgt = (unsigned)NWGc * (unsigned)(Tc + 2);
            for (;;) {
                unsigned s = 0;
                #pragma unroll
                for (int g = 0; g < 8; ++g)
                    s += __hip_atomic_load(&ctr[g * 16], __ATOMIC_RELAXED,
                                           __HIP_MEMORY_SCOPE_AGENT);
                if (s >= tgt) break;
                __builtin_amdgcn_s_sleep(1);
            }
        }
        wgbar();
        if (tid < Bc) {
            const float* h1f = h1g + (size_t)((Tc - 1) & 1) * SLAB;
            float s = fcb[0];
            for (int h = 0; h < HIDc; ++h)
                s = fmaf(ld_dev(h1f + h * Bc + tid), fcw[h], s);
            out[tid] = 1.f / (1.f + expf(-s));
        }
    }
}

extern "C" void kernel_launch(void* const* d_in, const int* in_sizes, int n_in,
                              void* d_out, int out_size, void* d_ws, size_t ws_size,
                              hipStream_t stream) {
    const int*   xp  = (const int*)d_in[0];
    const float* emb = (const float*)d_in[1];
    const float* W0  = (const float*)d_in[2];
    const float* b0  = (const float*)d_in[3];
    const float* W1  = (const float*)d_in[4];
    const float* b1  = (const float*)d_in[5];
    const float* fcw = (const float*)d_in[6];
    const float* fcb = (const float*)d_in[7];
    float* out = (float*)d_out;
    float* ws  = (float*)d_ws;

    if (ws_size < WS_END * sizeof(float)) return;  // loud fail: out stays poisoned

    static constexpr int ldsBytes = LDS_FLOATS * 4;
    hipFuncSetAttribute((const void*)lstm_persistent,
                        hipFuncAttributeMaxDynamicSharedMemorySize, ldsBytes);

    void* args[] = { (void*)&xp, (void*)&emb, (void*)&W0, (void*)&b0,
                     (void*)&W1, (void*)&b1, (void*)&fcw, (void*)&fcb,
                     (void*)&out, (void*)&ws };
    hipLaunchCooperativeKernel((void*)lstm_persistent, dim3(NWGc), dim3(THR),
                               args, ldsBytes, stream);
}

// Round 4
// 18195.686 us; speedup vs baseline: 1.8077x; 1.0260x over previous
//
#include <hip/hip_runtime.h>
#include <hip/hip_cooperative_groups.h>
#include <math.h>

namespace cg = cooperative_groups;

static constexpr int Bc   = 64;
static constexpr int Tc   = 512;
static constexpr int EMBc = 512;
static constexpr int HIDc = 512;
static constexpr int Kc   = 1024;
static constexpr int CH   = 128;
static constexpr int THR  = 256;
static constexpr int NWGc = 256;
static constexpr int SLAB = HIDc * Bc;   // 32768 floats = 128 KB

// ws layout (float indices)
static constexpr size_t WS_H0    = 0;                    // [3][SLAB] h0(t) at t%3
static constexpr size_t WS_H1    = WS_H0 + 3ull * SLAB;  // [2][SLAB] h1(t) at t&1
static constexpr size_t WS_XE    = WS_H1 + 2ull * SLAB;  // [3][SLAB] emb slab(t) at t%3
static constexpr size_t WS_CTR   = WS_XE + 3ull * SLAB;  // 8 counters, 64B apart
static constexpr size_t WS_EPOCH = WS_CTR + 128;         // epoch flag, own line
static constexpr size_t WS_END   = WS_EPOCH + 32;

// LDS layout (float indices)
static constexpr int LDS_W    = 0;                      // [16][1024] weights
static constexpr int LDS_COMB = 16 * Kc;                // [2][CH][Bc] staging dbuf
static constexpr int LDS_PRE  = LDS_COMB + 2 * CH * Bc; // [16][Bc] gate exchange
static constexpr int LDS_FLOATS = LDS_PRE + 16 * Bc;    // 33792 floats = 132 KB

typedef const __attribute__((address_space(1))) void* gas_t;
typedef __attribute__((address_space(3))) void* las_t;

__device__ __forceinline__ void st_dev(float* p, float v) {
    __hip_atomic_store(p, v, __ATOMIC_RELAXED, __HIP_MEMORY_SCOPE_AGENT);
}
__device__ __forceinline__ float ld_dev(const float* p) {
    return __hip_atomic_load(p, __ATOMIC_RELAXED, __HIP_MEMORY_SCOPE_AGENT);
}
__device__ __forceinline__ unsigned ld_devu(const unsigned* p) {
    return __hip_atomic_load(p, __ATOMIC_RELAXED, __HIP_MEMORY_SCOPE_AGENT);
}
template<int N> __device__ __forceinline__ void s_wait_vm() {
    asm volatile("s_waitcnt vmcnt(%0)" :: "n"(N) : "memory");
}
__device__ __forceinline__ void s_wait_lgkm() {
    asm volatile("s_waitcnt lgkmcnt(0)" ::: "memory");
}
__device__ __forceinline__ void wgbar() {
    asm volatile("" ::: "memory");
    __builtin_amdgcn_s_barrier();
    asm volatile("" ::: "memory");
}

__global__ __launch_bounds__(THR, 1)
void lstm_persistent(const int* __restrict__ xp,
                     const float* __restrict__ emb,
                     const float* __restrict__ W0,
                     const float* __restrict__ b0,
                     const float* __restrict__ W1,
                     const float* __restrict__ b1,
                     const float* __restrict__ fcw,
                     const float* __restrict__ fcb,
                     float* __restrict__ out,
                     float* __restrict__ ws)
{
    cg::grid_group grid = cg::this_grid();
    extern __shared__ float lds[];

    float*    h0g = ws + WS_H0;
    float*    h1g = ws + WS_H1;
    float*    xeg = ws + WS_XE;
    unsigned* ctr = (unsigned*)(ws + WS_CTR);
    unsigned* epo = (unsigned*)(ws + WS_EPOCH);

    const int  tid   = threadIdx.x;
    const int  wg    = blockIdx.x;
    const bool is_l0 = (wg < 128);
    const int  hw    = (is_l0 ? wg : wg - 128) * 4;
    const float* Wb  = is_l0 ? W0 : W1;
    const float* bb  = is_l0 ? b0 : b1;
    const int  b_    = tid & 63;
    const int  wv    = __builtin_amdgcn_readfirstlane(tid >> 6);

    // ---- init: zero h buffers (coherent stores), counters, slabs 0 & 1 ----
    for (size_t i = (size_t)wg * THR + tid; i < 5ull * SLAB; i += (size_t)NWGc * THR)
        st_dev(ws + i, 0.0f);
    if (wg == 0 && tid < 8)
        __hip_atomic_store(&ctr[tid * 16], 0u, __ATOMIC_RELAXED, __HIP_MEMORY_SCOPE_AGENT);
    if (wg == 0 && tid == 8)
        __hip_atomic_store(epo, 0u, __ATOMIC_RELAXED, __HIP_MEMORY_SCOPE_AGENT);

    const int rrow = tid >> 6;   // 0..3: this thread's k-row within WG's 4 rows
    if (is_l0) {
        #pragma unroll
        for (int wn = 0; wn < 2; ++wn) {
            const int kk  = hw + rrow;
            const int tok = xp[b_ * Tc + wn];
            float v = 0.0f;
            if (tok) v = emb[(size_t)tok * EMBc + kk];
            st_dev(xeg + (size_t)(wn % 3) * SLAB + kk * Bc + b_, v);
        }
    }

    // ---- preload this WG's 16 weight rows into LDS ----
    for (int r = 0; r < 16; ++r) {
        const float4* s = (const float4*)(Wb + (size_t)((r >> 2) * HIDc + hw + (r & 3)) * Kc);
        ((float4*)(lds + LDS_W + r * Kc))[tid] = s[tid];
    }
    float bias[4];
    #pragma unroll
    for (int j = 0; j < 4; ++j) bias[j] = bb[wv * HIDc + hw + j];

    grid.sync();   // only cg sync: init visible grid-wide

    const float* wr  = lds + LDS_W + (wv * 4) * Kc;
    float*       pre = lds + LDS_PRE;
    float cpriv = 0.0f;
    float acc[4];

    // stage 32 rows of chunk c from a [512][64] slab into comb[buf]
    auto stage = [&](int buf, const float* slabBase, int c) {
        const float* s = slabBase + (size_t)(c * CH + wv * 32) * Bc + b_;
        float*       d = lds + LDS_COMB + buf * CH * Bc + (wv * 32) * Bc;
        #pragma unroll
        for (int r = 0; r < 32; ++r)
            __builtin_amdgcn_global_load_lds((gas_t)(s + r * Bc),
                                             (las_t)(d + r * Bc), 4, 0, 16);
    };
    // GEMV over chunk in comb[buf], weight columns at global chunk cglob
    auto gemv = [&](int buf, int cglob) {
        const float* cb = lds + LDS_COMB + buf * CH * Bc;
        const float* wc = wr + cglob * CH;
        #pragma unroll 4
        for (int k4 = 0; k4 < CH / 4; ++k4) {
            const float x0 = cb[(k4 * 4 + 0) * Bc + b_];
            const float x1 = cb[(k4 * 4 + 1) * Bc + b_];
            const float x2 = cb[(k4 * 4 + 2) * Bc + b_];
            const float x3 = cb[(k4 * 4 + 3) * Bc + b_];
            const float4 q0 = *(const float4*)(wc + 0 * Kc + k4 * 4);
            const float4 q1 = *(const float4*)(wc + 1 * Kc + k4 * 4);
            const float4 q2 = *(const float4*)(wc + 2 * Kc + k4 * 4);
            const float4 q3 = *(const float4*)(wc + 3 * Kc + k4 * 4);
            acc[0] = fmaf(q0.w, x3, fmaf(q0.z, x2, fmaf(q0.y, x1, fmaf(q0.x, x0, acc[0]))));
            acc[1] = fmaf(q1.w, x3, fmaf(q1.z, x2, fmaf(q1.y, x1, fmaf(q1.x, x0, acc[1]))));
            acc[2] = fmaf(q2.w, x3, fmaf(q2.z, x2, fmaf(q2.y, x1, fmaf(q2.x, x0, acc[2]))));
            acc[3] = fmaf(q3.w, x3, fmaf(q3.z, x2, fmaf(q3.y, x1, fmaf(q3.x, x0, acc[3]))));
        }
    };
    // 4-chunk double-buffered half (chunks cbase..cbase+3 of the same slab)
    auto half = [&](const float* slabBase, int cbase) {
        stage(0, slabBase, cbase + 0);
        stage(1, slabBase, cbase + 1);
        s_wait_vm<32>(); wgbar();
        gemv(0, cbase + 0); s_wait_lgkm(); wgbar();
        stage(0, slabBase, cbase + 2);
        s_wait_vm<32>(); wgbar();
        gemv(1, cbase + 1); s_wait_lgkm(); wgbar();
        stage(1, slabBase, cbase + 3);
        s_wait_vm<32>(); wgbar();
        gemv(0, cbase + 2); s_wait_lgkm(); wgbar();
        s_wait_vm<0>();  wgbar();
        gemv(1, cbase + 3);
    };

    #pragma unroll 1
    for (int w = 0; w <= Tc + 1; ++w) {
        const bool a0  = is_l0 && (w < Tc);          // layer0 computes t=w
        const bool a1  = !is_l0 && (w >= 2);         // layer1 computes t=w-2
        const bool act = a0 || a1;

        acc[0] = acc[1] = acc[2] = acc[3] = 0.0f;

        // ---- PRE-HALF: barrier-independent input half (chunks 0..3) ----
        if (act) {
            const float* preBase = is_l0 ? (xeg + (size_t)(w % 3) * SLAB)
                                         : (h0g + (size_t)((w - 2) % 3) * SLAB);
            half(preBase, 0);
        }

        // ---- leader/epoch barrier w (relaxed; no cache maintenance) ----
        if (wg == 0) {
            if (tid == 0) {
                const unsigned tgt = (unsigned)NWGc * (unsigned)w;
                for (;;) {                       // sole poller of the 8 counters
                    unsigned s = 0;
                    #pragma unroll
                    for (int g = 0; g < 8; ++g)
                        s += ld_devu(&ctr[g * 16]);
                    if (s >= tgt) break;
                }
                __hip_atomic_store(epo, (unsigned)w, __ATOMIC_RELAXED,
                                   __HIP_MEMORY_SCOPE_AGENT);
            }
        } else {
            if (tid == 0) {
                while (ld_devu(epo) < (unsigned)w)   // single read-only line
                    __builtin_amdgcn_s_sleep(1);
            }
        }
        wgbar();

        // ---- POST-HALF: recurrent input half (chunks 4..7) + cell update ----
        if (act) {
            const float* postBase = is_l0 ? (h0g + (size_t)(((w - 1) + 3) % 3) * SLAB)
                                          : (h1g + (size_t)((w - 3) & 1) * SLAB);
            half(postBase, 4);

            pre[(wv * 4 + 0) * Bc + b_] = acc[0] + bias[0];
            pre[(wv * 4 + 1) * Bc + b_] = acc[1] + bias[1];
            pre[(wv * 4 + 2) * Bc + b_] = acc[2] + bias[2];
            pre[(wv * 4 + 3) * Bc + b_] = acc[3] + bias[3];
            s_wait_lgkm(); wgbar();
            const float p0 = pre[(0 * 4 + wv) * Bc + b_];
            const float p1 = pre[(1 * 4 + wv) * Bc + b_];
            const float p2 = pre[(2 * 4 + wv) * Bc + b_];
            const float p3 = pre[(3 * 4 + wv) * Bc + b_];
            const float ig = 1.f / (1.f + expf(-p0));
            const float fg = 1.f / (1.f + expf(-p1));
            const float og = 1.f / (1.f + expf(-p2));
            const float gg = fmaxf(p3, 0.f);
            cpriv = fg * cpriv + ig * gg;
            const float hn = og * fmaxf(cpriv, 0.f);
            float* hdst = is_l0 ? (h0g + (size_t)(w % 3) * SLAB)
                                : (h1g + (size_t)((w - 2) & 1) * SLAB);
            st_dev(hdst + (hw + wv) * Bc + b_, hn);
        }

        // ---- shared emb transpose for step w+2 (l0 WGs, 4 k-rows each) ----
        if (is_l0 && (w + 2) < Tc) {
            const int wn  = w + 2;
            const int kk  = hw + rrow;
            const int tok = xp[b_ * Tc + wn];
            float v = 0.0f;
            if (tok) v = emb[(size_t)tok * EMBc + kk];
            st_dev(xeg + (size_t)(wn % 3) * SLAB + kk * Bc + b_, v);
        }

        // ---- arrive for barrier w+1 ----
        s_wait_vm<0>();   // all write-through stores acked at coherent point
        wgbar();
        if (tid == 0)
            __hip_atomic_fetch_add(&ctr[(wg & 7) * 16], 1u, __ATOMIC_RELAXED,
                                   __HIP_MEMORY_SCOPE_AGENT);
    }

    // ---- final FC + sigmoid on h1(T-1) (slot (T-1)&1 = 1) ----
    if (wg == 0) {
        if (tid == 0) {
            const unsigned tgt = (unsigned)NWGc * (unsigned)(Tc + 2);
            for (;;) {
                unsigned s = 0;
                #pragma unroll
                for (int g = 0; g < 8; ++g)
                    s += ld_devu(&ctr[g * 16]);
                if (s >= tgt) break;
            }
        }
        wgbar();
        if (tid < Bc) {
            const float* h1f = h1g + (size_t)((Tc - 1) & 1) * SLAB;
            float s = fcb[0];
            for (int h = 0; h < HIDc; ++h)
                s = fmaf(ld_dev(h1f + h * Bc + tid), fcw[h], s);
            out[tid] = 1.f / (1.f + expf(-s));
        }
    }
}

extern "C" void kernel_launch(void* const* d_in, const int* in_sizes, int n_in,
                              void* d_out, int out_size, void* d_ws, size_t ws_size,
                              hipStream_t stream) {
    const int*   xp  = (const int*)d_in[0];
    const float* emb = (const float*)d_in[1];
    const float* W0  = (const float*)d_in[2];
    const float* b0  = (const float*)d_in[3];
    const float* W1  = (const float*)d_in[4];
    const float* b1  = (const float*)d_in[5];
    const float* fcw = (const float*)d_in[6];
    const float* fcb = (const float*)d_in[7];
    float* out = (float*)d_out;
    float* ws  = (float*)d_ws;

    if (ws_size < WS_END * sizeof(float)) return;  // loud fail: out stays poisoned

    static constexpr int ldsBytes = LDS_FLOATS * 4;
    hipFuncSetAttribute((const void*)lstm_persistent,
                        hipFuncAttributeMaxDynamicSharedMemorySize, ldsBytes);

    void* args[] = { (void*)&xp, (void*)&emb, (void*)&W0, (void*)&b0,
                     (void*)&W1, (void*)&b1, (void*)&fcw, (void*)&fcb,
                     (void*)&out, (void*)&ws };
    hipLaunchCooperativeKernel((void*)lstm_persistent, dim3(NWGc), dim3(THR),
                               args, ldsBytes, stream);
}

// Round 5
// 17446.188 us; speedup vs baseline: 1.8853x; 1.0430x over previous
//
#include <hip/hip_runtime.h>
#include <hip/hip_cooperative_groups.h>
#include <math.h>

namespace cg = cooperative_groups;

static constexpr int Bc   = 64;
static constexpr int Tc   = 512;
static constexpr int EMBc = 512;
static constexpr int HIDc = 512;
static constexpr int Kc   = 1024;
static constexpr int CH   = 128;
static constexpr int THR  = 256;
static constexpr int NWGc = 256;
static constexpr int SLAB = HIDc * Bc;   // 32768 floats = 128 KB

// ws layout (float indices)
static constexpr size_t WS_H0    = 0;                    // [3][SLAB] h0(t) at t%3
static constexpr size_t WS_H1    = WS_H0 + 3ull * SLAB;  // [2][SLAB] h1(t) at t&1
static constexpr size_t WS_XE    = WS_H1 + 2ull * SLAB;  // [3][SLAB] emb slab(t) at t%3
static constexpr size_t WS_CTR   = WS_XE + 3ull * SLAB;  // 8 counters, 64B apart
static constexpr size_t WS_EPOCH = WS_CTR + 128;         // epoch flag, own line
static constexpr size_t WS_END   = WS_EPOCH + 32;

// LDS layout (float indices): weights [16][1024], then 3 staging buffers
// [CH][Bc] each. The 4 KB gate-exchange 'pre' region ALIASES buffer 0
// (proven consumed-before-reuse by the barrier structure).
static constexpr int LDS_W    = 0;
static constexpr int LDS_COMB = 16 * Kc;                 // 3 bufs of CH*Bc
static constexpr int LDS_FLOATS = LDS_COMB + 3 * CH * Bc; // 40960 floats = 160 KB

typedef const __attribute__((address_space(1))) void* gas_t;
typedef __attribute__((address_space(3))) void* las_t;

__device__ __forceinline__ void st_dev(float* p, float v) {
    __hip_atomic_store(p, v, __ATOMIC_RELAXED, __HIP_MEMORY_SCOPE_AGENT);
}
__device__ __forceinline__ float ld_dev(const float* p) {
    return __hip_atomic_load(p, __ATOMIC_RELAXED, __HIP_MEMORY_SCOPE_AGENT);
}
__device__ __forceinline__ unsigned ld_devu(const unsigned* p) {
    return __hip_atomic_load(p, __ATOMIC_RELAXED, __HIP_MEMORY_SCOPE_AGENT);
}
template<int N> __device__ __forceinline__ void s_wait_vm() {
    asm volatile("s_waitcnt vmcnt(%0)" :: "n"(N) : "memory");
}
__device__ __forceinline__ void s_wait_lgkm() {
    asm volatile("s_waitcnt lgkmcnt(0)" ::: "memory");
}
__device__ __forceinline__ void wgbar() {
    asm volatile("" ::: "memory");
    __builtin_amdgcn_s_barrier();
    asm volatile("" ::: "memory");
}

__global__ __launch_bounds__(THR, 1)
void lstm_persistent(const int* __restrict__ xp,
                     const float* __restrict__ emb,
                     const float* __restrict__ W0,
                     const float* __restrict__ b0,
                     const float* __restrict__ W1,
                     const float* __restrict__ b1,
                     const float* __restrict__ fcw,
                     const float* __restrict__ fcb,
                     float* __restrict__ out,
                     float* __restrict__ ws)
{
    cg::grid_group grid = cg::this_grid();
    extern __shared__ float lds[];

    float*    h0g = ws + WS_H0;
    float*    h1g = ws + WS_H1;
    float*    xeg = ws + WS_XE;
    unsigned* ctr = (unsigned*)(ws + WS_CTR);
    unsigned* epo = (unsigned*)(ws + WS_EPOCH);

    const int  tid   = threadIdx.x;
    const int  wg    = blockIdx.x;
    const bool is_l0 = (wg < 128);
    const int  hw    = (is_l0 ? wg : wg - 128) * 4;
    const float* Wb  = is_l0 ? W0 : W1;
    const float* bb  = is_l0 ? b0 : b1;
    const int  b_    = tid & 63;
    const int  wv    = __builtin_amdgcn_readfirstlane(tid >> 6);

    // ---- init: zero h buffers, counters, emb slabs 0 & 1 ----
    for (size_t i = (size_t)wg * THR + tid; i < 5ull * SLAB; i += (size_t)NWGc * THR)
        st_dev(ws + i, 0.0f);
    if (wg == 0 && tid < 8)
        __hip_atomic_store(&ctr[tid * 16], 0u, __ATOMIC_RELAXED, __HIP_MEMORY_SCOPE_AGENT);
    if (wg == 0 && tid == 8)
        __hip_atomic_store(epo, 0u, __ATOMIC_RELAXED, __HIP_MEMORY_SCOPE_AGENT);

    const int rrow = tid >> 6;
    if (is_l0) {
        #pragma unroll
        for (int wn = 0; wn < 2; ++wn) {
            const int kk  = hw + rrow;
            const int tok = xp[b_ * Tc + wn];
            float v = 0.0f;
            if (tok) v = emb[(size_t)tok * EMBc + kk];
            st_dev(xeg + (size_t)(wn % 3) * SLAB + kk * Bc + b_, v);
        }
    }

    // ---- preload this WG's 16 weight rows into LDS ----
    for (int r = 0; r < 16; ++r) {
        const float4* s = (const float4*)(Wb + (size_t)((r >> 2) * HIDc + hw + (r & 3)) * Kc);
        ((float4*)(lds + LDS_W + r * Kc))[tid] = s[tid];
    }
    float bias[4];
    #pragma unroll
    for (int j = 0; j < 4; ++j) bias[j] = bb[wv * HIDc + hw + j];

    grid.sync();   // init visible grid-wide

    const float* wr  = lds + LDS_W + (wv * 4) * Kc;
    float*       pre = lds + LDS_COMB;        // ALIASES buffer 0
    float cpriv = 0.0f;
    float acc[4];

    // stage chunk c of a [512][64] slab into buf: 8 x global_load_lds(16B)
    // per wave (wave wv owns rows [wv*32, wv*32+32) = 8 KB contiguous)
    auto stageV = [&](int buf, const float* slabBase, int c) {
        const char* sb = (const char*)(slabBase + (size_t)c * CH * Bc)
                         + (size_t)wv * 8192 + (size_t)(tid & 63) * 16;
        char* db = (char*)(lds + LDS_COMB + buf * CH * Bc) + wv * 8192;
        #pragma unroll
        for (int i = 0; i < 8; ++i)
            __builtin_amdgcn_global_load_lds((gas_t)(sb + i * 1024),
                                             (las_t)(db + i * 1024), 16, 0, 16);
    };
    auto gemv = [&](int buf, int cglob) {
        const float* cb = lds + LDS_COMB + buf * CH * Bc;
        const float* wc = wr + cglob * CH;
        #pragma unroll 4
        for (int k4 = 0; k4 < CH / 4; ++k4) {
            const float x0 = cb[(k4 * 4 + 0) * Bc + b_];
            const float x1 = cb[(k4 * 4 + 1) * Bc + b_];
            const float x2 = cb[(k4 * 4 + 2) * Bc + b_];
            const float x3 = cb[(k4 * 4 + 3) * Bc + b_];
            const float4 q0 = *(const float4*)(wc + 0 * Kc + k4 * 4);
            const float4 q1 = *(const float4*)(wc + 1 * Kc + k4 * 4);
            const float4 q2 = *(const float4*)(wc + 2 * Kc + k4 * 4);
            const float4 q3 = *(const float4*)(wc + 3 * Kc + k4 * 4);
            acc[0] = fmaf(q0.w, x3, fmaf(q0.z, x2, fmaf(q0.y, x1, fmaf(q0.x, x0, acc[0]))));
            acc[1] = fmaf(q1.w, x3, fmaf(q1.z, x2, fmaf(q1.y, x1, fmaf(q1.x, x0, acc[1]))));
            acc[2] = fmaf(q2.w, x3, fmaf(q2.z, x2, fmaf(q2.y, x1, fmaf(q2.x, x0, acc[2]))));
            acc[3] = fmaf(q3.w, x3, fmaf(q3.z, x2, fmaf(q3.y, x1, fmaf(q3.x, x0, acc[3]))));
        }
    };
    // 4 chunks, 3-deep pipeline; local chunk j -> buf j%3 (0,1,2,0).
    // Caller provides a barrier after the final gemv before buffers are reused.
    auto half = [&](const float* slabBase, int cbase) {
        stageV(0, slabBase, cbase + 0);
        stageV(1, slabBase, cbase + 1);
        stageV(2, slabBase, cbase + 2);            // 24 in flight
        s_wait_vm<16>(); wgbar();                  // c0 landed everywhere
        gemv(0, cbase + 0);
        wgbar();                                   // buf0 consumed by all
        stageV(0, slabBase, cbase + 3);
        s_wait_vm<16>(); wgbar();                  // c1 landed
        gemv(1, cbase + 1);
        s_wait_vm<8>();  wgbar();                  // c2 landed
        gemv(2, cbase + 2);
        s_wait_vm<0>();  wgbar();                  // c3 landed
        gemv(0, cbase + 3);
    };

    #pragma unroll 1
    for (int w = 0; w <= Tc + 1; ++w) {
        const bool a0  = is_l0 && (w < Tc);          // layer0 computes t=w
        const bool a1  = !is_l0 && (w >= 2);         // layer1 computes t=w-2
        const bool act = a0 || a1;

        acc[0] = acc[1] = acc[2] = acc[3] = 0.0f;

        // ---- PRE-HALF: barrier-independent input half (chunks 0..3) ----
        if (act) {
            const float* preBase = is_l0 ? (xeg + (size_t)(w % 3) * SLAB)
                                         : (h0g + (size_t)((w - 2) % 3) * SLAB);
            half(preBase, 0);
        }

        // ---- leader/epoch barrier w ----
        if (wg == 0) {
            if (tid == 0) {
                const unsigned tgt = (unsigned)NWGc * (unsigned)w;
                for (;;) {
                    unsigned s = 0;
                    #pragma unroll
                    for (int g = 0; g < 8; ++g)
                        s += ld_devu(&ctr[g * 16]);
                    if (s >= tgt) break;
                }
                __hip_atomic_store(epo, (unsigned)w, __ATOMIC_RELAXED,
                                   __HIP_MEMORY_SCOPE_AGENT);
            }
        } else {
            if (tid == 0) {
                while (ld_devu(epo) < (unsigned)w)
                    __builtin_amdgcn_s_sleep(1);
            }
        }
        wgbar();   // also serves as the pre-half -> post-half buffer release

        // ---- POST-HALF: recurrent input half (chunks 4..7) + cell update ----
        if (act) {
            const float* postBase = is_l0 ? (h0g + (size_t)(((w - 1) + 3) % 3) * SLAB)
                                          : (h1g + (size_t)((w - 3) & 1) * SLAB);
            half(postBase, 4);

            wgbar();   // all waves done reading buf0 before pre (alias) write
            pre[(wv * 4 + 0) * Bc + b_] = acc[0] + bias[0];
            pre[(wv * 4 + 1) * Bc + b_] = acc[1] + bias[1];
            pre[(wv * 4 + 2) * Bc + b_] = acc[2] + bias[2];
            pre[(wv * 4 + 3) * Bc + b_] = acc[3] + bias[3];
            s_wait_lgkm(); wgbar();
            const float p0 = pre[(0 * 4 + wv) * Bc + b_];
            const float p1 = pre[(1 * 4 + wv) * Bc + b_];
            const float p2 = pre[(2 * 4 + wv) * Bc + b_];
            const float p3 = pre[(3 * 4 + wv) * Bc + b_];
            const float ig = 1.f / (1.f + expf(-p0));
            const float fg = 1.f / (1.f + expf(-p1));
            const float og = 1.f / (1.f + expf(-p2));
            const float gg = fmaxf(p3, 0.f);
            cpriv = fg * cpriv + ig * gg;
            const float hn = og * fmaxf(cpriv, 0.f);
            float* hdst = is_l0 ? (h0g + (size_t)(w % 3) * SLAB)
                                : (h1g + (size_t)((w - 2) & 1) * SLAB);
            st_dev(hdst + (hw + wv) * Bc + b_, hn);
        }

        // ---- shared emb transpose for step w+2 (l0 WGs, 4 k-rows each) ----
        if (is_l0 && (w + 2) < Tc) {
            const int wn  = w + 2;
            const int kk  = hw + rrow;
            const int tok = xp[b_ * Tc + wn];
            float v = 0.0f;
            if (tok) v = emb[(size_t)tok * EMBc + kk];
            st_dev(xeg + (size_t)(wn % 3) * SLAB + kk * Bc + b_, v);
        }

        // ---- arrive for barrier w+1 ----
        s_wait_vm<0>();
        wgbar();
        if (tid == 0)
            __hip_atomic_fetch_add(&ctr[(wg & 7) * 16], 1u, __ATOMIC_RELAXED,
                                   __HIP_MEMORY_SCOPE_AGENT);
    }

    // ---- final FC + sigmoid on h1(T-1) ----
    if (wg == 0) {
        if (tid == 0) {
            const unsigned tgt = (unsigned)NWGc * (unsigned)(Tc + 2);
            for (;;) {
                unsigned s = 0;
                #pragma unroll
                for (int g = 0; g < 8; ++g)
                    s += ld_devu(&ctr[g * 16]);
                if (s >= tgt) break;
            }
        }
        wgbar();
        if (tid < Bc) {
            const float* h1f = h1g + (size_t)((Tc - 1) & 1) * SLAB;
            float s = fcb[0];
            for (int h = 0; h < HIDc; ++h)
                s = fmaf(ld_dev(h1f + h * Bc + tid), fcw[h], s);
            out[tid] = 1.f / (1.f + expf(-s));
        }
    }
}

extern "C" void kernel_launch(void* const* d_in, const int* in_sizes, int n_in,
                              void* d_out, int out_size, void* d_ws, size_t ws_size,
                              hipStream_t stream) {
    const int*   xp  = (const int*)d_in[0];
    const float* emb = (const float*)d_in[1];
    const float* W0  = (const float*)d_in[2];
    const float* b0  = (const float*)d_in[3];
    const float* W1  = (const float*)d_in[4];
    const float* b1  = (const float*)d_in[5];
    const float* fcw = (const float*)d_in[6];
    const float* fcb = (const float*)d_in[7];
    float* out = (float*)d_out;
    float* ws  = (float*)d_ws;

    if (ws_size < WS_END * sizeof(float)) return;  // loud fail: out stays poisoned

    static constexpr int ldsBytes = LDS_FLOATS * 4;   // 163840 = 160 KB
    hipFuncSetAttribute((const void*)lstm_persistent,
                        hipFuncAttributeMaxDynamicSharedMemorySize, ldsBytes);

    void* args[] = { (void*)&xp, (void*)&emb, (void*)&W0, (void*)&b0,
                     (void*)&W1, (void*)&b1, (void*)&fcw, (void*)&fcb,
                     (void*)&out, (void*)&ws };
    hipLaunchCooperativeKernel((void*)lstm_persistent, dim3(NWGc), dim3(THR),
                               args, ldsBytes, stream);
}

// Round 8
// 5132.676 us; speedup vs baseline: 6.4083x; 3.3990x over previous
//
#include <hip/hip_runtime.h>
#include <hip/hip_bf16.h>
#include <math.h>

typedef __attribute__((ext_vector_type(8))) short bf16x8;
typedef __attribute__((ext_vector_type(4))) float f32x4;

static constexpr int Tc = 512, HIDc = 512;
static constexpr int NWGc = 256, THR = 256;

// ws byte offsets. Slabs are bf16 [64 batch][512 k] = 64 KB each.
static constexpr size_t WSB_H0  = 0;                     // [3] h0(t) at t%3
static constexpr size_t WSB_H1  = WSB_H0 + 3ull * 65536; // [2] h1(t) at t&1
static constexpr size_t WSB_XE  = WSB_H1 + 2ull * 65536; // [3] emb slab(t) at t%3
static constexpr size_t WSB_CTR = WSB_XE + 3ull * 65536; // 8 counters, 64B apart
static constexpr size_t WSB_EPO = WSB_CTR + 512;         // epoch flag, own line
static constexpr size_t WSB_FLG = WSB_EPO + 64;          // 256 init flags, 64B apart
static constexpr size_t WSB_END = WSB_FLG + 256 * 64;

static constexpr unsigned FMAGIC = 0x1357acedu;  // init-done flag value
static constexpr unsigned EPBASE = 0x40000000u;  // epoch base (post-init)

__device__ __forceinline__ unsigned ld_devu(const unsigned* p) {
    return __hip_atomic_load(p, __ATOMIC_RELAXED, __HIP_MEMORY_SCOPE_AGENT);
}
__device__ __forceinline__ unsigned long long ld_devu64(const unsigned long long* p) {
    return __hip_atomic_load(p, __ATOMIC_RELAXED, __HIP_MEMORY_SCOPE_AGENT);
}
__device__ __forceinline__ void st_devu(unsigned* p, unsigned v) {
    __hip_atomic_store(p, v, __ATOMIC_RELAXED, __HIP_MEMORY_SCOPE_AGENT);
}
template<int N> __device__ __forceinline__ void s_wait_vm() {
    asm volatile("s_waitcnt vmcnt(%0)" :: "n"(N) : "memory");
}
__device__ __forceinline__ void s_wait_lgkm() {
    asm volatile("s_waitcnt lgkmcnt(0)" ::: "memory");
}
__device__ __forceinline__ void wgbar() {
    asm volatile("" ::: "memory");
    __builtin_amdgcn_s_barrier();
    asm volatile("" ::: "memory");
}
__device__ __forceinline__ unsigned short bfc(float f) {
    __hip_bfloat16 h = __float2bfloat16(f);
    return *(unsigned short*)&h;
}
__device__ __forceinline__ float bf2f(unsigned short u) {
    __hip_bfloat16 h; *(unsigned short*)&h = u;
    return __bfloat162float(h);
}

__global__ __launch_bounds__(THR, 1)
void lstm_persistent(const int* __restrict__ xp,
                     const float* __restrict__ emb,
                     const float* __restrict__ W0,
                     const float* __restrict__ b0,
                     const float* __restrict__ W1,
                     const float* __restrict__ b1,
                     const float* __restrict__ fcw,
                     const float* __restrict__ fcb,
                     float* __restrict__ out,
                     float* __restrict__ ws)
{
    char* wsc = (char*)ws;

    unsigned* ctr = (unsigned*)(wsc + WSB_CTR);
    unsigned* epo = (unsigned*)(wsc + WSB_EPO);
    unsigned* flg = (unsigned*)(wsc + WSB_FLG);

    __shared__ float preF[16 * 68];   // gate preacts [w-row][batch], pad 68
    __shared__ float hexF[4 * 64];    // h exchange [h_local][batch]

    const int  tid   = threadIdx.x;
    const int  wg    = blockIdx.x;
    const bool is_l0 = (wg < 128);
    const int  hw    = (is_l0 ? wg : wg - 128) * 4;
    const float* Wb  = is_l0 ? W0 : W1;
    const float* bb  = is_l0 ? b0 : b1;
    const int  b_    = tid & 63;
    const int  wv    = __builtin_amdgcn_readfirstlane(tid >> 6);
    // MFMA lane decomposition (16x16x32): n = lane&15, q = lane>>4
    const int  n = tid & 15;
    const int  q = (tid & 63) >> 4;
    // this lane's A-row byte offset in a [64][512] bf16 slab (1024 B rows)
    const size_t rowB = (size_t)(wv * 16 + n) * 1024 + (size_t)q * 16;

    // ---- diagnostic sentinel: proves the kernel launched (overwritten later)
    if (wg == 0 && tid < 64) out[tid] = 0.25f;

    // ---- init: zero the 5 h slabs ----
    {
        unsigned long long* hz = (unsigned long long*)(wsc + WSB_H0);
        const int i = wg * THR + tid;
        if (i < 5 * 8192)
            __hip_atomic_store(hz + i, 0ull, __ATOMIC_RELAXED, __HIP_MEMORY_SCOPE_AGENT);
    }

    // ---- emb production (l0 WGs; 2 WGs per batch row) ----
    const int be = wg >> 1;                       // batch row produced
    const int p2 = ((wg & 1) << 7) + (tid & 127); // u32-pair index 0..255
    auto emb_produce = [&](int wn) {
        if (tid < 128) {
            const int tok = xp[be * Tc + wn];
            float2 v = make_float2(0.f, 0.f);
            if (tok) v = *(const float2*)(emb + (size_t)tok * 512 + p2 * 2);
            unsigned u = (unsigned)bfc(v.x) | ((unsigned)bfc(v.y) << 16);
            st_devu((unsigned*)(wsc + WSB_XE + (size_t)(wn % 3) * 65536) + be * 256 + p2, u);
        }
    };
    if (is_l0) { emb_produce(0); emb_produce(1); }

    // ---- B-fragments: wave's 16 weight rows (w-row n), bf16, in VGPRs ----
    // frag f covers k in [f*32, f*32+32); lane holds k = f*32 + q*8 .. +8
    bf16x8 bw[32];
    {
        const float* wrow = Wb + (size_t)((n >> 2) * HIDc + hw + (n & 3)) * 1024;
        #pragma unroll
        for (int f = 0; f < 32; ++f) {
            const int k0 = f * 32 + q * 8;
            const float4 u0 = *(const float4*)(wrow + k0);
            const float4 u1 = *(const float4*)(wrow + k0 + 4);
            union { unsigned short us[8]; bf16x8 v; } pk;
            pk.us[0] = bfc(u0.x); pk.us[1] = bfc(u0.y);
            pk.us[2] = bfc(u0.z); pk.us[3] = bfc(u0.w);
            pk.us[4] = bfc(u1.x); pk.us[5] = bfc(u1.y);
            pk.us[6] = bfc(u1.z); pk.us[7] = bfc(u1.w);
            bw[f] = pk.v;
        }
    }
    const float bias_n = bb[(n >> 2) * HIDc + hw + (n & 3)];

    // ---- init barrier (poison-tolerant, no cooperative launch) ----
    s_wait_vm<0>();   // this thread's init stores acked at coherent point
    wgbar();          // whole WG drained
    if (tid == 0) st_devu(&flg[wg * 16], FMAGIC);
    if (wg == 0 && tid == 0) {
        for (int g = 0; g < NWGc; ++g) {
            while (ld_devu(&flg[g * 16]) != FMAGIC) __builtin_amdgcn_s_sleep(1);
        }
        #pragma unroll
        for (int g = 0; g < 8; ++g) st_devu(&ctr[g * 16], 0u);
        s_wait_vm<0>();                 // ctr zeroes acked before epoch publish
        st_devu(epo, EPBASE);
    } else if (tid == 0) {
        while (ld_devu(epo) != EPBASE) __builtin_amdgcn_s_sleep(1);
    }
    wgbar();          // all waves of WG gated on init-done

    float cpriv = 0.0f;

    // load one A-fragment: 16 B of slab row (wv*16+n), chunk cloc, k-step s
    auto ldfrag = [&](const char* slab, int cloc, int s) -> bf16x8 {
        const unsigned long long* p =
            (const unsigned long long*)(slab + rowB + (size_t)cloc * 256 + (size_t)s * 64);
        union { unsigned long long u[2]; bf16x8 v; } r;
        r.u[0] = ld_devu64(p);
        r.u[1] = ld_devu64(p + 1);
        return r.v;
    };

    #pragma unroll 1
    for (int w = 0; w <= Tc + 1; ++w) {
        const bool a0  = is_l0 && (w < Tc);     // layer0 computes t=w
        const bool a1  = !is_l0 && (w >= 2);    // layer1 computes t=w-2
        const bool act = a0 || a1;

        // ---- A-half fragment loads (barrier-independent input), pre-spin ----
        bf16x8 fa[16];
        if (act) {
            const char* slabA = is_l0
                ? (wsc + WSB_XE + (size_t)(w % 3) * 65536)            // emb(w)
                : (wsc + WSB_H0 + (size_t)((w - 2) % 3) * 65536);     // h0(w-2)
            #pragma unroll
            for (int c = 0; c < 4; ++c) {
                #pragma unroll
                for (int s = 0; s < 4; ++s)
                    fa[c * 4 + s] = ldfrag(slabA, c, s);
            }
        }

        // ---- leader/epoch barrier w ----
        if (wg == 0) {
            if (tid == 0) {
                const unsigned tgt = (unsigned)NWGc * (unsigned)w;
                for (;;) {
                    unsigned s = 0;
                    #pragma unroll
                    for (int g = 0; g < 8; ++g) s += ld_devu(&ctr[g * 16]);
                    if (s >= tgt) break;
                }
                st_devu(epo, EPBASE + 1u + (unsigned)w);
            }
        } else {
            if (tid == 0) {
                while (ld_devu(epo) < EPBASE + 1u + (unsigned)w)
                    __builtin_amdgcn_s_sleep(1);
            }
        }
        wgbar();

        if (act) {
            // ---- B-half fragment loads (recurrent input) ----
            const char* slabB = is_l0
                ? (wsc + WSB_H0 + (size_t)((w + 2) % 3) * 65536)      // h0(w-1)
                : (wsc + WSB_H1 + (size_t)((w - 3) & 1) * 65536);     // h1(w-3)
            bf16x8 fb[16];
            #pragma unroll
            for (int c = 0; c < 4; ++c) {
                #pragma unroll
                for (int s = 0; s < 4; ++s)
                    fb[c * 4 + s] = ldfrag(slabB, c, s);
            }

            f32x4 acc = {0.f, 0.f, 0.f, 0.f};
            #pragma unroll
            for (int i = 0; i < 16; ++i)
                acc = __builtin_amdgcn_mfma_f32_16x16x32_bf16(fa[i], bw[i], acc, 0, 0, 0);
            #pragma unroll
            for (int i = 0; i < 16; ++i)
                acc = __builtin_amdgcn_mfma_f32_16x16x32_bf16(fb[i], bw[16 + i], acc, 0, 0, 0);

            // ---- gate exchange: lane reg r holds D[batch q*4+r][w-row n] ----
            *(f32x4*)(preF + (size_t)n * 68 + wv * 16 + q * 4) = acc + bias_n;
            s_wait_lgkm(); wgbar();

            // cell update: thread (b_, h_local = wv); gate g at w-row g*4+wv
            const float pI = preF[(0 * 4 + wv) * 68 + b_];
            const float pF = preF[(1 * 4 + wv) * 68 + b_];
            const float pO = preF[(2 * 4 + wv) * 68 + b_];
            const float pG = preF[(3 * 4 + wv) * 68 + b_];
            const float ig = 1.f / (1.f + expf(-pI));
            const float fg = 1.f / (1.f + expf(-pF));
            const float og = 1.f / (1.f + expf(-pO));
            const float gg = fmaxf(pG, 0.f);
            cpriv = fg * cpriv + ig * gg;
            const float hn = og * fmaxf(cpriv, 0.f);
            hexF[wv * 64 + b_] = hn;
            s_wait_lgkm(); wgbar();

            // h-write: wave 0 packs 4 bf16 -> one 8 B store per batch row
            if (tid < 64) {
                unsigned long long pk = 0;
                #pragma unroll
                for (int jj = 0; jj < 4; ++jj)
                    pk |= (unsigned long long)bfc(hexF[jj * 64 + tid]) << (16 * jj);
                unsigned short* hdst = is_l0
                    ? (unsigned short*)(wsc + WSB_H0 + (size_t)(w % 3) * 65536)
                    : (unsigned short*)(wsc + WSB_H1 + (size_t)((w - 2) & 1) * 65536);
                __hip_atomic_store((unsigned long long*)(hdst + (size_t)tid * 512 + hw),
                                   pk, __ATOMIC_RELAXED, __HIP_MEMORY_SCOPE_AGENT);
            }
        }

        // ---- emb production for step w+2 (l0 WGs, coalesced pairs) ----
        if (is_l0 && (w + 2) < Tc) emb_produce(w + 2);

        // ---- arrive for barrier w+1 ----
        s_wait_vm<0>();   // h-store + emb stores acked at coherent point
        wgbar();
        if (tid == 0)
            __hip_atomic_fetch_add(&ctr[(wg & 7) * 16], 1u, __ATOMIC_RELAXED,
                                   __HIP_MEMORY_SCOPE_AGENT);
    }

    // ---- final FC + sigmoid on h1(Tc-1) ----
    if (wg == 0) {
        if (tid == 0) {
            const unsigned tgt = (unsigned)NWGc * (unsigned)(Tc + 2);
            for (;;) {
                unsigned s = 0;
                #pragma unroll
                for (int g = 0; g < 8; ++g) s += ld_devu(&ctr[g * 16]);
                if (s >= tgt) break;
            }
        }
        wgbar();
        if (tid < 64) {
            const unsigned short* h1f =
                (const unsigned short*)(wsc + WSB_H1 + (size_t)((Tc - 1) & 1) * 65536)
                + (size_t)tid * 512;
            float s = fcb[0];
            for (int h = 0; h < HIDc; h += 4) {
                const unsigned long long u = ld_devu64((const unsigned long long*)(h1f + h));
                s = fmaf(bf2f((unsigned short)(u        & 0xffff)), fcw[h + 0], s);
                s = fmaf(bf2f((unsigned short)((u >> 16) & 0xffff)), fcw[h + 1], s);
                s = fmaf(bf2f((unsigned short)((u >> 32) & 0xffff)), fcw[h + 2], s);
                s = fmaf(bf2f((unsigned short)((u >> 48) & 0xffff)), fcw[h + 3], s);
            }
            out[tid] = 1.f / (1.f + expf(-s));
        }
    }
}

extern "C" void kernel_launch(void* const* d_in, const int* in_sizes, int n_in,
                              void* d_out, int out_size, void* d_ws, size_t ws_size,
                              hipStream_t stream) {
    const int*   xp  = (const int*)d_in[0];
    const float* emb = (const float*)d_in[1];
    const float* W0  = (const float*)d_in[2];
    const float* b0  = (const float*)d_in[3];
    const float* W1  = (const float*)d_in[4];
    const float* b1  = (const float*)d_in[5];
    const float* fcw = (const float*)d_in[6];
    const float* fcb = (const float*)d_in[7];
    float* out = (float*)d_out;
    float* ws  = (float*)d_ws;

    if (ws_size < WSB_END) return;  // loud fail: out stays poisoned

    // Plain launch: 256 WGs x 256 thr, 1 WG/CU on 256 CUs -> co-resident.
    lstm_persistent<<<dim3(NWGc), dim3(THR), 0, stream>>>(
        xp, emb, W0, b0, W1, b1, fcw, fcb, out, ws);
}